// Round 6
// baseline (109.920 us; speedup 1.0000x reference)
//
#include <hip/hip_runtime.h>
#include <stdint.h>

#define NROWS 8192
#define DD 128
#define EPS 1e-8f
#define LOG2E 1.4426950408889634f

// main kernel tiling
#define SPLIT 16       // column splits (blocks cooperating per row-strip)
#define RPB 128        // rows per block (4 waves x 2 strips x 16 rows)
#define NSUB ((NROWS / SPLIT) / 16)   // 32 16-col subtiles per block
#define NORM_BLOCKS (NROWS / 4)
#define PACK_BLOCKS 3200   // 100 classes * 128 u64-words / 4 waves

typedef __bf16 bf16x8 __attribute__((ext_vector_type(8)));
typedef float f32x4 __attribute__((ext_vector_type(4)));

__device__ __forceinline__ unsigned int f2bf(float f) {
  union { float f; unsigned int u; } v; v.f = f;
  unsigned int u = v.u;
  return (u + 0x7fffu + ((u >> 16) & 1u)) >> 16;
}
__device__ __forceinline__ float bf2f(unsigned int b) {
  union { unsigned int u; float f; } v; v.u = b << 16;
  return v.f;
}
__device__ __forceinline__ bf16x8 u2b(uint4 u) {
  union { uint4 u; bf16x8 b; } v; v.u = u; return v.b;
}

// Kernel 1 (blocks < NORM_BLOCKS): per-row normalize.
//   xnA  = bf16(x/||x|| * log2e/T)  (A operand pre-scaled: e = exp2(acc))
//   xnBt = bf16(x/||x||) in MFMA B-FRAGMENT ORDER:
//          chunk(row j, kstep, q) at (j>>4)*4096 + kstep*1024 + q*256 + (j&15)*16
//          (so main's B loads are perfectly coalesced dwordx4 per lane (q,c))
//   p = exp2(cos(x,proxy)*log2e/T)  [margin cancels in num/den ratio]
//   e_self = exp2(<xnA_bf16, xnB_bf16>)  (MFMA diagonal, subtracted in loss)
//   mii = negmask[label_i][i]; zero tot/msk/out.
// Kernel 1 (blocks >= NORM_BLOCKS): ballot-pack negmask into u32 bit-words:
//   packed[class*256 + j/32] bit (j&31) = (negmask[class][j] != 0)
__global__ __launch_bounds__(256) void norm_kernel(
    const float* __restrict__ x, const float* __restrict__ pr,
    const float* __restrict__ nm, const int* __restrict__ lb,
    const float* __restrict__ tptr,
    unsigned short* __restrict__ xnA, unsigned char* __restrict__ xnBt,
    float* __restrict__ p, float* __restrict__ eself, float* __restrict__ mii,
    float* __restrict__ tot, float* __restrict__ msk,
    unsigned int* __restrict__ packed, float* __restrict__ out)
{
  int wave = threadIdx.x >> 6, lane = threadIdx.x & 63;
  int bx = blockIdx.x;

  if (bx >= NORM_BLOCKS) {
    // ---- mask pack branch ----
    int widx = (bx - NORM_BLOCKS) * 4 + wave;   // 0..12799
    int cls = widx >> 7;                        // 0..99
    int w64 = widx & 127;                       // u64-word within class
    float v = nm[(size_t)cls * NROWS + w64 * 64 + lane];
    unsigned long long b = __ballot(v != 0.0f);
    if (lane == 0) {
      packed[cls * 256 + w64 * 2] = (unsigned int)b;
      packed[cls * 256 + w64 * 2 + 1] = (unsigned int)(b >> 32);
    }
    return;
  }

  int row = bx * 4 + wave;
  float2 xv = ((const float2*)(x + (size_t)row * DD))[lane];
  float2 pv = ((const float2*)(pr + (size_t)row * DD))[lane];
  float sx = xv.x * xv.x + xv.y * xv.y;
  float sp = pv.x * pv.x + pv.y * pv.y;
  float dp = xv.x * pv.x + xv.y * pv.y;
  #pragma unroll
  for (int m = 1; m < 64; m <<= 1) {
    sx += __shfl_xor(sx, m);
    sp += __shfl_xor(sp, m);
    dp += __shfl_xor(dp, m);
  }
  float inx = 1.f / fmaxf(sqrtf(sx), EPS);
  float inp = 1.f / fmaxf(sqrtf(sp), EPS);
  float s1 = LOG2E / tptr[0];

  unsigned int a0 = f2bf(xv.x * inx * s1), a1 = f2bf(xv.y * inx * s1);
  unsigned int b0 = f2bf(xv.x * inx),      b1 = f2bf(xv.y * inx);
  ((unsigned int*)(xnA + (size_t)row * DD))[lane] = a0 | (a1 << 16);

  // fragment-order B store: lane holds elements 2*lane, 2*lane+1
  //   = kstep*32 + q*8 + pos*2 with kstep=lane>>4, q=(lane>>2)&3, pos=lane&3
  {
    int kstep = lane >> 4, qq = (lane >> 2) & 3, pos = lane & 3;
    unsigned int dst = ((unsigned int)(row >> 4)) * 4096u + kstep * 1024u +
                       qq * 256u + (row & 15) * 16u + pos * 4u;
    *(unsigned int*)(xnBt + dst) = b0 | (b1 << 16);
  }

  // self-sim with the SAME rounded values the MFMA will see
  float ss = bf2f(a0) * bf2f(b0) + bf2f(a1) * bf2f(b1);
  #pragma unroll
  for (int m = 1; m < 64; m <<= 1) ss += __shfl_xor(ss, m);

  if (lane == 0) {
    p[row] = __builtin_amdgcn_exp2f(dp * inx * inp * s1);
    eself[row] = __builtin_amdgcn_exp2f(ss);
    mii[row] = nm[(size_t)lb[row] * NROWS + row];
    tot[row] = 0.f;
    msk[row] = 0.f;
    if (row == 0) out[0] = 0.f;
  }
}

// Kernel 2: fused sim-GEMM + exp + masked/total row-sum accumulation.
// Block = 256 threads = 4 waves; each wave owns 2 strips of 16 rows (RPB=128).
// Grid: (NROWS/RPB, SPLIT). NO LDS, NO BARRIERS: B fragments are loaded
// directly from the fragment-ordered xnBt with perfectly coalesced dwordx4
// (lane (q,c) -> base + q*256 + c*16), prefetched one subtile ahead;
// L1 absorbs the cross-wave reuse. Masks bit-packed u32 per 32 cols.
__global__ __launch_bounds__(256, 4) void main_kernel(
    const unsigned short* __restrict__ xnA_u, const unsigned char* __restrict__ xnBt,
    const unsigned int* __restrict__ packed, const int* __restrict__ labels,
    float* __restrict__ tot, float* __restrict__ msk)
{
  int tid = threadIdx.x;
  int wave = tid >> 6, lane = tid & 63;
  int q = lane >> 4, c = lane & 15;
  int rb0 = blockIdx.x * RPB + wave * 16;  // strip 0 row base
  int rb1 = rb0 + 64;                      // strip 1 row base

  const bf16x8* xnvA = (const bf16x8*)xnA_u;

  // A fragments (held in registers for the whole column loop)
  // layout: m = lane&15, k = (lane>>4)*8 + j  per 32-wide K step
  bf16x8 a0[4], a1[4];
  {
    const bf16x8* b = xnvA + (size_t)(rb0 + c) * (DD / 8) + q;
    a0[0] = b[0]; a0[1] = b[4]; a0[2] = b[8]; a0[3] = b[12];
  }
  {
    const bf16x8* b = xnvA + (size_t)(rb1 + c) * (DD / 8) + q;
    a1[0] = b[0]; a1[1] = b[4]; a1[2] = b[8]; a1[3] = b[12];
  }

  int jb = blockIdx.y * (NROWS / SPLIT);

  // Epilogue rows for this lane: row_local = q*4 + k, col = (t&1)*16 + c
  int r0[4], r1[4];
  unsigned int offP0[4], offP1[4];        // packed-mask word offsets
  #pragma unroll
  for (int k = 0; k < 4; k++) {
    r0[k] = rb0 + q * 4 + k;
    r1[k] = rb1 + q * 4 + k;
    offP0[k] = (unsigned int)labels[r0[k]] * 256u + (unsigned int)(jb >> 5);
    offP1[k] = (unsigned int)labels[r1[k]] * 256u + (unsigned int)(jb >> 5);
  }
  float t0[4] = {0, 0, 0, 0}, m0[4] = {0, 0, 0, 0};
  float t1[4] = {0, 0, 0, 0}, m1[4] = {0, 0, 0, 0};

  // B fragment base for this lane: coalesced 16B per lane, 1KB per wave-load
  const unsigned char* gB = xnBt + (size_t)(jb >> 4) * 4096 +
                            (unsigned int)(q * 256 + c * 16);

  // prefetch subtile 0
  uint4 nb0 = *(const uint4*)(gB);
  uint4 nb1 = *(const uint4*)(gB + 1024);
  uint4 nb2 = *(const uint4*)(gB + 2048);
  uint4 nb3 = *(const uint4*)(gB + 3072);

  for (int t = 0; t < NSUB; t++) {
    bf16x8 b0 = u2b(nb0), b1 = u2b(nb1), b2 = u2b(nb2), b3 = u2b(nb3);

    // issue subtile t+1 loads (land during this subtile's compute)
    if (t + 1 < NSUB) {
      const unsigned char* gb = gB + (size_t)(t + 1) * 4096;
      nb0 = *(const uint4*)(gb);
      nb1 = *(const uint4*)(gb + 1024);
      nb2 = *(const uint4*)(gb + 2048);
      nb3 = *(const uint4*)(gb + 3072);
    }

    // mask words for this 32-col group (L1-resident dword gathers)
    unsigned int wc0[4], wc1[4];
    int g = t >> 1;
    #pragma unroll
    for (int k = 0; k < 4; k++) {
      wc0[k] = packed[offP0[k] + g];
      wc1[k] = packed[offP1[k] + g];
    }

    f32x4 acc0 = {0, 0, 0, 0};
    f32x4 acc1 = {0, 0, 0, 0};
    acc0 = __builtin_amdgcn_mfma_f32_16x16x32_bf16(a0[0], b0, acc0, 0, 0, 0);
    acc1 = __builtin_amdgcn_mfma_f32_16x16x32_bf16(a1[0], b0, acc1, 0, 0, 0);
    acc0 = __builtin_amdgcn_mfma_f32_16x16x32_bf16(a0[1], b1, acc0, 0, 0, 0);
    acc1 = __builtin_amdgcn_mfma_f32_16x16x32_bf16(a1[1], b1, acc1, 0, 0, 0);
    acc0 = __builtin_amdgcn_mfma_f32_16x16x32_bf16(a0[2], b2, acc0, 0, 0, 0);
    acc1 = __builtin_amdgcn_mfma_f32_16x16x32_bf16(a1[2], b2, acc1, 0, 0, 0);
    acc0 = __builtin_amdgcn_mfma_f32_16x16x32_bf16(a0[3], b3, acc0, 0, 0, 0);
    acc1 = __builtin_amdgcn_mfma_f32_16x16x32_bf16(a1[3], b3, acc1, 0, 0, 0);

    int pos = (t & 1) * 16 + c;   // bit position in the packed u32 word
    #pragma unroll
    for (int k = 0; k < 4; k++) {
      float e = __builtin_amdgcn_exp2f(acc0[k]);
      t0[k] += e;
      m0[k] = fmaf(e, (float)((wc0[k] >> pos) & 1u), m0[k]);
    }
    #pragma unroll
    for (int k = 0; k < 4; k++) {
      float e = __builtin_amdgcn_exp2f(acc1[k]);
      t1[k] += e;
      m1[k] = fmaf(e, (float)((wc1[k] >> pos) & 1u), m1[k]);
    }
  }

  // Reduce across the 16 lanes (c) sharing each q group.
  #pragma unroll
  for (int sh = 1; sh < 16; sh <<= 1) {
    #pragma unroll
    for (int k = 0; k < 4; k++) {
      t0[k] += __shfl_xor(t0[k], sh);
      m0[k] += __shfl_xor(m0[k], sh);
      t1[k] += __shfl_xor(t1[k], sh);
      m1[k] += __shfl_xor(m1[k], sh);
    }
  }
  if (c == 0) {
    #pragma unroll
    for (int k = 0; k < 4; k++) {
      atomicAdd(&tot[r0[k]], t0[k]);
      atomicAdd(&msk[r0[k]], m0[k]);
      atomicAdd(&tot[r1[k]], t1[k]);
      atomicAdd(&msk[r1[k]], m1[k]);
    }
  }
}

// Kernel 3: loss = mean(log(p+tot') - log(p+msk')), diagonal subtracted here.
__global__ __launch_bounds__(256) void loss_kernel(
    const float* __restrict__ p, const float* __restrict__ tot,
    const float* __restrict__ msk, const float* __restrict__ eself,
    const float* __restrict__ mii, float* __restrict__ out)
{
  __shared__ float sd[4];
  int r = blockIdx.x * 256 + threadIdx.x;
  float pi = p[r];
  float es = eself[r];
  float t = tot[r] - es;                 // remove diagonal from total sum
  float m = msk[r] - es * mii[r];        // remove diagonal from masked sum
  float v = __builtin_amdgcn_logf(pi + t) - __builtin_amdgcn_logf(pi + m);
  float s = v * (1.0f / (LOG2E * (float)NROWS));
  #pragma unroll
  for (int sh = 1; sh < 64; sh <<= 1) s += __shfl_xor(s, sh);
  int wave = threadIdx.x >> 6, lane = threadIdx.x & 63;
  if (lane == 0) sd[wave] = s;
  __syncthreads();
  if (threadIdx.x == 0) atomicAdd(out, sd[0] + sd[1] + sd[2] + sd[3]);
}

extern "C" void kernel_launch(void* const* d_in, const int* in_sizes, int n_in,
                              void* d_out, int out_size, void* d_ws, size_t ws_size,
                              hipStream_t stream) {
  const float* x  = (const float*)d_in[0];   // inst_embed [N,D]
  const float* pr = (const float*)d_in[1];   // proxy [N,D]
  const float* nm = (const float*)d_in[2];   // negative_mask [100,N]
  const int*   lb = (const int*)d_in[3];     // labels [N]
  const float* tp = (const float*)d_in[4];   // temperature
  // margin (d_in[5]) cancels algebraically in numerator/denominator

  char* ws = (char*)d_ws;
  unsigned short* xnA = (unsigned short*)ws;                        // 2 MB
  unsigned char* xnBt = (unsigned char*)(xnA + (size_t)NROWS * DD); // 2 MB
  float* p     = (float*)(xnBt + (size_t)NROWS * DD * 2);
  float* tot   = p + NROWS;
  float* msk   = tot + NROWS;
  float* eself = msk + NROWS;
  float* miiv  = eself + NROWS;
  unsigned int* packed = (unsigned int*)(miiv + NROWS);             // 102.4 KB
  float* out = (float*)d_out;

  norm_kernel<<<NORM_BLOCKS + PACK_BLOCKS, 256, 0, stream>>>(
      x, pr, nm, lb, tp, xnA, xnBt, p, eself, miiv, tot, msk, packed, out);
  main_kernel<<<dim3(NROWS / RPB, SPLIT), 256, 0, stream>>>(xnA, xnBt, packed,
                                                            lb, tot, msk);
  loss_kernel<<<NROWS / 256, 256, 0, stream>>>(p, tot, msk, eself, miiv, out);
}